// Round 1
// baseline (395.373 us; speedup 1.0000x reference)
//
#include <hip/hip_runtime.h>
#include <hip/hip_fp16.h>

#define BB 4
#define HH 192
#define WW 640
#define CC 32
#define SS 32
#define PXB 64    // pixels per block (one row segment; 640 % 64 == 0)
#define MAXW 152  // staged source-pixel window; LDS = 2*MAXW*64B + 1KB = 20KB -> 8 blocks/CU

typedef _Float16 half2n __attribute__((ext_vector_type(2)));

#if defined(__has_builtin)
#if __has_builtin(__builtin_amdgcn_fdot2)
#define HAS_FDOT2 1
#endif
#endif

__device__ __forceinline__ float fdot2_acc(__half2 a, __half2 b, float acc) {
#ifdef HAS_FDOT2
    return __builtin_amdgcn_fdot2(__builtin_bit_cast(half2n, a),
                                  __builtin_bit_cast(half2n, b), acc, false);
#else
    const float2 af = __half22float2(a);
    const float2 bf = __half22float2(b);
    return acc + af.x * bf.x + af.y * bf.y;
#endif
}

__device__ __forceinline__ unsigned pk2(float w) {
    // half2(w, w) as a packed uint
    return (unsigned)__builtin_bit_cast(unsigned short, __float2half_rn(w)) * 0x10001u;
}

// x (fp32, 63MB) -> fp16 copy in workspace (31.5MB). Re-run every call.
__global__ __launch_bounds__(256) void convert_x_kernel(const float* __restrict__ x,
                                                        __half* __restrict__ xh) {
    const size_t i = ((size_t)blockIdx.x * 256 + threadIdx.x) * 8;
    const float4 f0 = *(const float4*)(x + i);
    const float4 f1 = *(const float4*)(x + i + 4);
    uint4 u;
    u.x = __builtin_bit_cast(unsigned, __floats2half2_rn(f0.x, f0.y));
    u.y = __builtin_bit_cast(unsigned, __floats2half2_rn(f0.z, f0.w));
    u.z = __builtin_bit_cast(unsigned, __floats2half2_rn(f1.x, f1.y));
    u.w = __builtin_bit_cast(unsigned, __floats2half2_rn(f1.z, f1.w));
    *(uint4*)(xh + i) = u;
}

// R8: row-pair LDS staging. Key fact: sy (hence the source row pair and the
// y-direction weights) is UNIFORM across the block for each step. So per step
// we cooperatively stage comb[p] = wy0*row0[p] + wy1*row1[p] (fp16, 64B/px)
// into LDS — each source byte crosses L2 exactly once per block-step, fully
// coalesced — then each lane reads comb at x0/x1 via 2x ds_read_b128 instead
// of 4 global gathers. Halves the L2 gather traffic that bounded R7.
// Double-buffered comb: 1 barrier/step. Per-step uniforms precomputed by
// threads 0..31 into a 1KB LDS table. Fallback to direct gather if the
// source window exceeds MAXW pixels (large |alpha|; uniform branch).
__global__ __launch_bounds__(256, 8) void corr_kernel(
    const __half* __restrict__ xh, const float* __restrict__ y,
    const float* __restrict__ origin, const float* __restrict__ focal,
    const float* __restrict__ T12, float* __restrict__ out)
{
    // sU[s] = { alpha, dkx, xlo, width4 }   sV[s] = { r0byte, r1byte, wy0pk, wy1pk }
    __shared__ uint4 sU[SS];
    __shared__ uint4 sV[SS];
    __shared__ uint4 sComb[2][MAXW * 4];   // wy-combined source rows, fp16, 16B chunks

    const int tid  = threadIdx.x;
    const int lane = tid & 63;
    const int wave = tid >> 6;
    const int slot = lane >> 2;   // pixel within wave (0..15)
    const int cg   = lane & 3;    // channel group: fp16 channels [8cg, 8cg+8)

    const int p0 = blockIdx.x * PXB;
    const int w0 = p0 % WW;
    const int h  = (p0 / WW) % HH;
    const int b  = p0 / (WW * HH);

    // ---- per-step uniforms (one thread per step) ----
    if (tid < SS) {
        const float tz = T12[b * 3 + 2];
        const float kx = tz * origin[b * 2 + 0] + focal[b * 2 + 0] * T12[b * 3 + 0];
        const float ky = tz * origin[b * 2 + 1] + focal[b * 2 + 1] * T12[b * 3 + 1];
        const float sf = (float)tid;
        // D = s/(1+s*tz); s=0 -> D=0 automatically (matches reference).
        const float D = sf * __builtin_amdgcn_rcpf(1.0f + sf * tz);
        const float alpha = 1.0f - D * tz;
        const float dkx = D * kx;
        const float dky = D * ky;

        const float syv = alpha * (float)h + dky;
        const float y0f = floorf(syv);
        const float fy  = syv - y0f;
        const int   y0  = (int)y0f;
        const int   y1  = y0 + 1;
        const float wy0 = (y0 >= 0 && y0 < HH) ? (1.0f - fy) : 0.0f;
        const float wy1 = (y1 >= 0 && y1 < HH) ? fy : 0.0f;
        const int   cy0 = min(max(y0, 0), HH - 1);
        const int   cy1 = min(max(y1, 0), HH - 1);

        // source x window for this block (sx is linear in pixel index)
        const float sxa = alpha * (float)w0 + dkx;
        const float sxb = alpha * (float)(w0 + PXB - 1) + dkx;
        const int xlo = (int)floorf(fminf(sxa, sxb));
        const int xhi = (int)floorf(fmaxf(sxa, sxb)) + 1;
        const int width4 = (xhi - xlo + 1) * 4;   // 16B chunks to stage

        uint4 U, V;
        U.x = __builtin_bit_cast(unsigned, alpha);
        U.y = __builtin_bit_cast(unsigned, dkx);
        U.z = (unsigned)xlo;
        U.w = (unsigned)width4;
        V.x = (unsigned)((cy0 * WW) << 6);   // row byte base in fp16 image
        V.y = (unsigned)((cy1 * WW) << 6);
        V.z = pk2(wy0);
        V.w = pk2(wy1);
        sU[tid] = U;
        sV[tid] = V;
    }

    const int pme = p0 + wave * 16 + slot;
    // This lane's 8 y channels as 4 x half2
    __half2 yh[4];
    {
        const float4 ya = *(const float4*)(y + (size_t)pme * CC + cg * 8);
        const float4 yb = *(const float4*)(y + (size_t)pme * CC + cg * 8 + 4);
        yh[0] = __floats2half2_rn(ya.x, ya.y);
        yh[1] = __floats2half2_rn(ya.z, ya.w);
        yh[2] = __floats2half2_rn(yb.x, yb.y);
        yh[3] = __floats2half2_rn(yb.z, yb.w);
    }

    const char* xbase = (const char*)(xh + (size_t)b * HH * WW * CC);
    const int cgb = cg * 16;                       // byte offset within 64B pixel
    const float pxf = (float)(w0 + wave * 16 + slot);
    float* outp = out + (size_t)pme * SS;

    __syncthreads();   // uniforms table ready

#pragma unroll 1
    for (int s = 0; s < SS; ++s) {
        const uint4 U = sU[s];                     // broadcast ds_read
        const uint4 V = sV[s];
        const float alpha  = __builtin_bit_cast(float, U.x);
        const float dkx    = __builtin_bit_cast(float, U.y);
        const int   xlo    = (int)U.z;
        const int   width4 = (int)U.w;
        const int   buf    = s & 1;
        const bool  fits   = (width4 <= MAXW * 4);

        // ---- stage: comb = wy0*row0 + wy1*row1, coalesced, each byte once ----
        if (fits) {
            const __half2 wy0h = __builtin_bit_cast(__half2, V.z);
            const __half2 wy1h = __builtin_bit_cast(__half2, V.w);
            for (int c = tid; c < width4; c += 256) {
                const int cpx = min(max(xlo + (c >> 2), 0), WW - 1);
                const unsigned po = (unsigned)((cpx << 6) + ((c & 3) << 4));
                const uint4 a  = *(const uint4*)(xbase + (size_t)(V.x + po));
                const uint4 bq = *(const uint4*)(xbase + (size_t)(V.y + po));
                uint4 o;
#pragma unroll
                for (int i = 0; i < 4; ++i) {
                    __half2 r = __hmul2(__builtin_bit_cast(__half2, (&a.x)[i]), wy0h);
                    r = __hfma2(__builtin_bit_cast(__half2, (&bq.x)[i]), wy1h, r);
                    (&o.x)[i] = __builtin_bit_cast(unsigned, r);
                }
                sComb[buf][c] = o;
            }
        }
        __syncthreads();   // comb(s) ready; also protects buf reuse 2 steps apart

        // ---- consume: per-pixel x interpolation + channel dot ----
        const float sx  = alpha * pxf + dkx;
        const float x0f = floorf(sx);
        const float fx  = sx - x0f;
        const int   x0  = (int)x0f;
        const int   x1  = x0 + 1;
        const float wx0f = (x0 >= 0 && x0 < WW) ? (1.0f - fx) : 0.0f;
        const float wx1f = (x1 >= 0 && x1 < WW) ? fx : 0.0f;
        const __half2 wx0 = __builtin_bit_cast(__half2, pk2(wx0f));
        const __half2 wx1 = __builtin_bit_cast(__half2, pk2(wx1f));
        const int cx0 = min(max(x0, 0), WW - 1);
        const int cx1 = min(max(x1, 0), WW - 1);

        float acc = 0.0f;
        if (fits) {
            const int wlim = (width4 >> 2) - 1;
            const int l0 = min(max(cx0 - xlo, 0), wlim);
            const int l1 = min(max(cx1 - xlo, 0), wlim);
            const uint4 ca = sComb[buf][l0 * 4 + cg];
            const uint4 cb = sComb[buf][l1 * 4 + cg];
#pragma unroll
            for (int i = 0; i < 4; ++i) {
                __half2 v = __hmul2(__builtin_bit_cast(__half2, (&ca.x)[i]), wx0);
                v = __hfma2(__builtin_bit_cast(__half2, (&cb.x)[i]), wx1, v);
                acc = fdot2_acc(v, yh[i], acc);
            }
        } else {
            // rare fallback: direct 4-corner gather (window too wide for LDS)
            const __half2 wy0h = __builtin_bit_cast(__half2, V.z);
            const __half2 wy1h = __builtin_bit_cast(__half2, V.w);
            const uint4 a  = *(const uint4*)(xbase + (size_t)(V.x + (unsigned)((cx0 << 6) + cgb)));
            const uint4 bq = *(const uint4*)(xbase + (size_t)(V.x + (unsigned)((cx1 << 6) + cgb)));
            const uint4 c2 = *(const uint4*)(xbase + (size_t)(V.y + (unsigned)((cx0 << 6) + cgb)));
            const uint4 d  = *(const uint4*)(xbase + (size_t)(V.y + (unsigned)((cx1 << 6) + cgb)));
#pragma unroll
            for (int i = 0; i < 4; ++i) {
                __half2 top = __hmul2(__builtin_bit_cast(__half2, (&a.x)[i]), wx0);
                top = __hfma2(__builtin_bit_cast(__half2, (&bq.x)[i]), wx1, top);
                __half2 bot = __hmul2(__builtin_bit_cast(__half2, (&c2.x)[i]), wx0);
                bot = __hfma2(__builtin_bit_cast(__half2, (&d.x)[i]), wx1, bot);
                __half2 v = __hmul2(top, wy0h);
                v = __hfma2(bot, wy1h, v);
                acc = fdot2_acc(v, yh[i], acc);
            }
        }

        // Reduce over the 4 channel-lanes (hardware quad -> DPP quad_perm).
        acc += __shfl_xor(acc, 1, 64);
        acc += __shfl_xor(acc, 2, 64);
        if ((s & 3) == cg) outp[s] = acc * (1.0f / 32.0f);
    }
}

extern "C" void kernel_launch(void* const* d_in, const int* in_sizes, int n_in,
                              void* d_out, int out_size, void* d_ws, size_t ws_size,
                              hipStream_t stream) {
    const float* x = (const float*)d_in[0];
    const float* y = (const float*)d_in[1];
    const float* origin = (const float*)d_in[2];
    const float* focal = (const float*)d_in[3];
    const float* T12 = (const float*)d_in[4];
    float* out = (float*)d_out;
    __half* xh = (__half*)d_ws;   // needs BB*HH*WW*CC*2 = 31.5 MB

    const int nelem = BB * HH * WW * CC;          // 15,728,640
    convert_x_kernel<<<nelem / (256 * 8), 256, 0, stream>>>(x, xh);

    const int npix = BB * HH * WW;                // 491,520
    corr_kernel<<<npix / PXB, 256, 0, stream>>>(xh, y, origin, focal, T12, out);
}

// Round 2
// 313.968 us; speedup vs baseline: 1.2593x; 1.2593x over previous
//
#include <hip/hip_runtime.h>
#include <hip/hip_fp16.h>

#define BB 4
#define HH 192
#define WW 640
#define CC 32
#define SS 32
#define PXB 64    // pixels per block (one row segment; 640 % 64 == 0)
#define MAXW 152  // staged source-pixel window; LDS = 2*MAXW*64B + 1KB = 20KB -> 8 blocks/CU

typedef _Float16 half2n __attribute__((ext_vector_type(2)));

#if defined(__has_builtin)
#if __has_builtin(__builtin_amdgcn_fdot2)
#define HAS_FDOT2 1
#endif
#endif

__device__ __forceinline__ float fdot2_acc(__half2 a, __half2 b, float acc) {
#ifdef HAS_FDOT2
    return __builtin_amdgcn_fdot2(__builtin_bit_cast(half2n, a),
                                  __builtin_bit_cast(half2n, b), acc, false);
#else
    const float2 af = __half22float2(a);
    const float2 bf = __half22float2(b);
    return acc + af.x * bf.x + af.y * bf.y;
#endif
}

__device__ __forceinline__ unsigned pk2(float w) {
    // half2(w, w) as a packed uint
    return (unsigned)__builtin_bit_cast(unsigned short, __float2half_rn(w)) * 0x10001u;
}

// LDS chunk swizzle: XOR low-2 index bits with pixel's low-2 bits so the 16
// pixel-slots of one cg spread over 8 bank-groups instead of aliasing on 1.
__device__ __forceinline__ int swz(int c) { return c ^ ((c >> 2) & 3); }

// x (fp32, 63MB) -> fp16 copy in workspace (31.5MB). Re-run every call.
__global__ __launch_bounds__(256) void convert_x_kernel(const float* __restrict__ x,
                                                        __half* __restrict__ xh) {
    const size_t i = ((size_t)blockIdx.x * 256 + threadIdx.x) * 8;
    const float4 f0 = *(const float4*)(x + i);
    const float4 f1 = *(const float4*)(x + i + 4);
    uint4 u;
    u.x = __builtin_bit_cast(unsigned, __floats2half2_rn(f0.x, f0.y));
    u.y = __builtin_bit_cast(unsigned, __floats2half2_rn(f0.z, f0.w));
    u.z = __builtin_bit_cast(unsigned, __floats2half2_rn(f1.x, f1.y));
    u.w = __builtin_bit_cast(unsigned, __floats2half2_rn(f1.z, f1.w));
    *(uint4*)(xh + i) = u;
}

// R9: R8's row-pair LDS staging + two fixes the counters demanded:
//  (1) outputs accumulate in registers (res[8], static idx) and are written
//      once as 2x float4 per lane -> quad fills the pixel's 128B line fully.
//      R8's per-step 4B scattered writes thrashed against the staging stream
//      in L2: WRITE_SIZE 650MB (10x ideal) + RMW re-fetches.
//  (2) sComb chunks XOR-swizzled (swz) -> consume ds_read_b128 spreads over
//      8 bank-groups (was: 16 slots on the same 4 banks, 4.8M conflict cyc).
__global__ __launch_bounds__(256, 8) void corr_kernel(
    const __half* __restrict__ xh, const float* __restrict__ y,
    const float* __restrict__ origin, const float* __restrict__ focal,
    const float* __restrict__ T12, float* __restrict__ out)
{
    // sU[s] = { alpha, dkx, xlo, width4 }   sV[s] = { r0byte, r1byte, wy0pk, wy1pk }
    __shared__ uint4 sU[SS];
    __shared__ uint4 sV[SS];
    __shared__ uint4 sComb[2][MAXW * 4];   // wy-combined source rows, fp16, 16B chunks

    const int tid  = threadIdx.x;
    const int lane = tid & 63;
    const int wave = tid >> 6;
    const int slot = lane >> 2;   // pixel within wave (0..15)
    const int cg   = lane & 3;    // channel group: fp16 channels [8cg, 8cg+8)

    const int p0 = blockIdx.x * PXB;
    const int w0 = p0 % WW;
    const int h  = (p0 / WW) % HH;
    const int b  = p0 / (WW * HH);

    // ---- per-step uniforms (one thread per step) ----
    if (tid < SS) {
        const float tz = T12[b * 3 + 2];
        const float kx = tz * origin[b * 2 + 0] + focal[b * 2 + 0] * T12[b * 3 + 0];
        const float ky = tz * origin[b * 2 + 1] + focal[b * 2 + 1] * T12[b * 3 + 1];
        const float sf = (float)tid;
        // D = s/(1+s*tz); s=0 -> D=0 automatically (matches reference).
        const float D = sf * __builtin_amdgcn_rcpf(1.0f + sf * tz);
        const float alpha = 1.0f - D * tz;
        const float dkx = D * kx;
        const float dky = D * ky;

        const float syv = alpha * (float)h + dky;
        const float y0f = floorf(syv);
        const float fy  = syv - y0f;
        const int   y0  = (int)y0f;
        const int   y1  = y0 + 1;
        const float wy0 = (y0 >= 0 && y0 < HH) ? (1.0f - fy) : 0.0f;
        const float wy1 = (y1 >= 0 && y1 < HH) ? fy : 0.0f;
        const int   cy0 = min(max(y0, 0), HH - 1);
        const int   cy1 = min(max(y1, 0), HH - 1);

        // source x window for this block (sx is linear in pixel index)
        const float sxa = alpha * (float)w0 + dkx;
        const float sxb = alpha * (float)(w0 + PXB - 1) + dkx;
        const int xlo = (int)floorf(fminf(sxa, sxb));
        const int xhi = (int)floorf(fmaxf(sxa, sxb)) + 1;
        const int width4 = (xhi - xlo + 1) * 4;   // 16B chunks to stage

        uint4 U, V;
        U.x = __builtin_bit_cast(unsigned, alpha);
        U.y = __builtin_bit_cast(unsigned, dkx);
        U.z = (unsigned)xlo;
        U.w = (unsigned)width4;
        V.x = (unsigned)((cy0 * WW) << 6);   // row byte base in fp16 image
        V.y = (unsigned)((cy1 * WW) << 6);
        V.z = pk2(wy0);
        V.w = pk2(wy1);
        sU[tid] = U;
        sV[tid] = V;
    }

    const int pme = p0 + wave * 16 + slot;
    // This lane's 8 y channels as 4 x half2
    __half2 yh[4];
    {
        const float4 ya = *(const float4*)(y + (size_t)pme * CC + cg * 8);
        const float4 yb = *(const float4*)(y + (size_t)pme * CC + cg * 8 + 4);
        yh[0] = __floats2half2_rn(ya.x, ya.y);
        yh[1] = __floats2half2_rn(ya.z, ya.w);
        yh[2] = __floats2half2_rn(yb.x, yb.y);
        yh[3] = __floats2half2_rn(yb.z, yb.w);
    }

    const char* xbase = (const char*)(xh + (size_t)b * HH * WW * CC);
    const int cgb = cg * 16;                       // byte offset within 64B pixel
    const float pxf = (float)(w0 + wave * 16 + slot);
    float* outp = out + (size_t)pme * SS;

    float res[8];                                  // steps 8*cg .. 8*cg+7

    __syncthreads();   // uniforms table ready

#pragma unroll 1
    for (int g = 0; g < 4; ++g) {
#pragma unroll
        for (int j = 0; j < 8; ++j) {
            const int s = g * 8 + j;
            const uint4 U = sU[s];                 // broadcast ds_read
            const uint4 V = sV[s];
            const float alpha  = __builtin_bit_cast(float, U.x);
            const float dkx    = __builtin_bit_cast(float, U.y);
            const int   xlo    = (int)U.z;
            const int   width4 = (int)U.w;
            const int   buf    = s & 1;
            const bool  fits   = (width4 <= MAXW * 4);

            // ---- stage: comb = wy0*row0 + wy1*row1, coalesced, once per byte
            if (fits) {
                const __half2 wy0h = __builtin_bit_cast(__half2, V.z);
                const __half2 wy1h = __builtin_bit_cast(__half2, V.w);
                for (int c = tid; c < width4; c += 256) {
                    const int cpx = min(max(xlo + (c >> 2), 0), WW - 1);
                    const unsigned po = (unsigned)((cpx << 6) + ((c & 3) << 4));
                    const uint4 a  = *(const uint4*)(xbase + (size_t)(V.x + po));
                    const uint4 bq = *(const uint4*)(xbase + (size_t)(V.y + po));
                    uint4 o;
#pragma unroll
                    for (int i = 0; i < 4; ++i) {
                        __half2 r = __hmul2(__builtin_bit_cast(__half2, (&a.x)[i]), wy0h);
                        r = __hfma2(__builtin_bit_cast(__half2, (&bq.x)[i]), wy1h, r);
                        (&o.x)[i] = __builtin_bit_cast(unsigned, r);
                    }
                    sComb[buf][swz(c)] = o;
                }
            }
            __syncthreads();   // comb(s) ready; buf reuse protected 2 steps apart

            // ---- consume: per-pixel x interpolation + channel dot ----
            const float sx  = alpha * pxf + dkx;
            const float x0f = floorf(sx);
            const float fx  = sx - x0f;
            const int   x0  = (int)x0f;
            const int   x1  = x0 + 1;
            const float wx0f = (x0 >= 0 && x0 < WW) ? (1.0f - fx) : 0.0f;
            const float wx1f = (x1 >= 0 && x1 < WW) ? fx : 0.0f;
            const __half2 wx0 = __builtin_bit_cast(__half2, pk2(wx0f));
            const __half2 wx1 = __builtin_bit_cast(__half2, pk2(wx1f));
            const int cx0 = min(max(x0, 0), WW - 1);
            const int cx1 = min(max(x1, 0), WW - 1);

            float acc = 0.0f;
            if (fits) {
                const int wlim = (width4 >> 2) - 1;
                const int l0 = min(max(cx0 - xlo, 0), wlim);
                const int l1 = min(max(cx1 - xlo, 0), wlim);
                const uint4 ca = sComb[buf][swz(l0 * 4 + cg)];
                const uint4 cb = sComb[buf][swz(l1 * 4 + cg)];
#pragma unroll
                for (int i = 0; i < 4; ++i) {
                    __half2 v = __hmul2(__builtin_bit_cast(__half2, (&ca.x)[i]), wx0);
                    v = __hfma2(__builtin_bit_cast(__half2, (&cb.x)[i]), wx1, v);
                    acc = fdot2_acc(v, yh[i], acc);
                }
            } else {
                // rare fallback: direct 4-corner gather (window too wide for LDS)
                const __half2 wy0h = __builtin_bit_cast(__half2, V.z);
                const __half2 wy1h = __builtin_bit_cast(__half2, V.w);
                const uint4 a  = *(const uint4*)(xbase + (size_t)(V.x + (unsigned)((cx0 << 6) + cgb)));
                const uint4 bq = *(const uint4*)(xbase + (size_t)(V.x + (unsigned)((cx1 << 6) + cgb)));
                const uint4 c2 = *(const uint4*)(xbase + (size_t)(V.y + (unsigned)((cx0 << 6) + cgb)));
                const uint4 d  = *(const uint4*)(xbase + (size_t)(V.y + (unsigned)((cx1 << 6) + cgb)));
#pragma unroll
                for (int i = 0; i < 4; ++i) {
                    __half2 top = __hmul2(__builtin_bit_cast(__half2, (&a.x)[i]), wx0);
                    top = __hfma2(__builtin_bit_cast(__half2, (&bq.x)[i]), wx1, top);
                    __half2 bot = __hmul2(__builtin_bit_cast(__half2, (&c2.x)[i]), wx0);
                    bot = __hfma2(__builtin_bit_cast(__half2, (&d.x)[i]), wx1, bot);
                    __half2 v = __hmul2(top, wy0h);
                    v = __hfma2(bot, wy1h, v);
                    acc = fdot2_acc(v, yh[i], acc);
                }
            }

            // Reduce over the 4 channel-lanes (hardware quad -> DPP quad_perm).
            acc += __shfl_xor(acc, 1, 64);
            acc += __shfl_xor(acc, 2, 64);
            // Lane keeps steps [8*cg, 8*cg+8): static res index (j), runtime guard.
            if (g == cg) res[j] = acc * (1.0f / 32.0f);
        }
    }

    // Coalesced epilogue: quad (cg=0..3) fills the pixel's full 128B line.
    float4 o0, o1;
    o0.x = res[0]; o0.y = res[1]; o0.z = res[2]; o0.w = res[3];
    o1.x = res[4]; o1.y = res[5]; o1.z = res[6]; o1.w = res[7];
    *(float4*)(outp + cg * 8)     = o0;
    *(float4*)(outp + cg * 8 + 4) = o1;
}

extern "C" void kernel_launch(void* const* d_in, const int* in_sizes, int n_in,
                              void* d_out, int out_size, void* d_ws, size_t ws_size,
                              hipStream_t stream) {
    const float* x = (const float*)d_in[0];
    const float* y = (const float*)d_in[1];
    const float* origin = (const float*)d_in[2];
    const float* focal = (const float*)d_in[3];
    const float* T12 = (const float*)d_in[4];
    float* out = (float*)d_out;
    __half* xh = (__half*)d_ws;   // needs BB*HH*WW*CC*2 = 31.5 MB

    const int nelem = BB * HH * WW * CC;          // 15,728,640
    convert_x_kernel<<<nelem / (256 * 8), 256, 0, stream>>>(x, xh);

    const int npix = BB * HH * WW;                // 491,520
    corr_kernel<<<npix / PXB, 256, 0, stream>>>(xh, y, origin, focal, T12, out);
}